// Round 3
// baseline (380.116 us; speedup 1.0000x reference)
//
#include <hip/hip_runtime.h>
#include <hip/hip_bf16.h>

#define HW_   (512 * 512)
#define B_    4
#define D_    64
#define NPIX  (B_ * HW_)          // 1048576
#define NW    19                  // within channels used (20 - 1)
#define NC    26                  // cross channels used  (27 - 1)
#define NLAB  (NW + NC)           // 45
#define NSEG  20                  // centroid segments
#define THREADS 256
#define TILE  THREADS             // 1 pixel per thread

// ---- macro label lists: every accumulator is a NAMED scalar (rule #20:
// arrays never survive to registers here; named SSA values always do) ----
#define LW(X)  X(0)X(1)X(2)X(3)X(4)X(5)X(6)X(7)X(8)X(9)X(10)X(11)X(12)X(13)X(14)X(15)X(16)X(17)X(18)
#define LWR(X) X(1)X(2)X(3)X(4)X(5)X(6)X(7)X(8)X(9)X(10)X(11)X(12)X(13)X(14)X(15)X(16)X(17)X(18)
#define LC(X)  X(19)X(20)X(21)X(22)X(23)X(24)X(25)X(26)X(27)X(28)X(29)X(30)X(31)X(32)X(33)X(34)X(35)X(36)X(37)X(38)X(39)X(40)X(41)X(42)X(43)X(44)
#define LCR(X) X(20)X(21)X(22)X(23)X(24)X(25)X(26)X(27)X(28)X(29)X(30)X(31)X(32)X(33)X(34)X(35)X(36)X(37)X(38)X(39)X(40)X(41)X(42)X(43)X(44)
#define LA(X)  LW(X) LC(X)

__global__ __launch_bounds__(THREADS, 4)
void fused_embed(const float* __restrict__ enc, const float* __restrict__ wW,
                 const float* __restrict__ wC, const int* __restrict__ targ,
                 float* __restrict__ out)
{
    __shared__ float sCent[NSEG][D_ + 1]; // +1 pad: bank = lab*65+c ≡ lab+c (mod 32)
    __shared__ int   sCount[NSEG];
    __shared__ float sRed[THREADS / 64];

    const int tid = threadIdx.x;

    for (int i = tid; i < NSEG * (D_ + 1); i += THREADS) (&sCent[0][0])[i] = 0.f;
    if (tid < NSEG) sCount[tid] = 0;
    __syncthreads();

    const int p   = blockIdx.x * TILE + tid;       // this thread's pixel
    const int b   = (blockIdx.x * TILE) / HW_;     // whole block inside one image
    const int hw0 = p - b * HW_;
    const float* fp = enc + (size_t)b * (D_ * HW_) + hw0;
    const int lab = targ[p];

#define DECL_ACC(n) float a##n = 0.f;
    LA(DECL_ACC)

    // weight row base: compile-time select per label
#define WPTR(n) (((n) < NW) ? (wW + (n) * D_) : (wC + ((n) - NW) * D_))

#pragma unroll 2
    for (int dc = 0; dc < D_ / 4; ++dc) {
        const float* fpc = fp + (size_t)dc * 4 * HW_;
        float f0 = fpc[0];
        float f1 = fpc[HW_];
        float f2 = fpc[2 * HW_];
        float f3 = fpc[3 * HW_];

        // centroid accumulation (ds_add_f32, no return)
        atomicAdd(&sCent[lab][dc * 4 + 0], f0);
        atomicAdd(&sCent[lab][dc * 4 + 1], f1);
        atomicAdd(&sCent[lab][dc * 4 + 2], f2);
        atomicAdd(&sCent[lab][dc * 4 + 3], f3);

        // wave-uniform weight reads -> scalar loads; v_fma takes 1 SGPR operand
#define FMA_ACC(n) { const float4 w = *(const float4*)(WPTR(n) + dc * 4); \
                     a##n = fmaf(w.w, f3, fmaf(w.z, f2, fmaf(w.y, f1, fmaf(w.x, f0, a##n)))); }
        LA(FMA_ACC)
#undef FMA_ACC
    }

    atomicAdd(&sCount[lab], 1);

    // ---- entropies over named scalars (T=1, alpha=beta=0.5) ----
    float lossAcc = 0.f;
    {   // within: a0..a18
        float m = a0;
#define MX(n) m = fmaxf(m, a##n);
        LWR(MX)
#undef MX
        float S = 0.f, Wt = 0.f;
#define ES(n) { float s = a##n - m; float e = __expf(s); S += e; Wt = fmaf(e, s, Wt); }
        LW(ES)
#undef ES
        lossAcc += __logf(S) - Wt / S;
    }
    {   // cross: a19..a44
        float m = a19;
#define MX(n) m = fmaxf(m, a##n);
        LCR(MX)
#undef MX
        float S = 0.f, Wt = 0.f;
#define ES(n) { float s = a##n - m; float e = __expf(s); S += e; Wt = fmaf(e, s, Wt); }
        LC(ES)
#undef ES
        lossAcc += __logf(S) - Wt / S;
    }

    // wave reduce (64 lanes)
#pragma unroll
    for (int off = 32; off; off >>= 1) lossAcc += __shfl_down(lossAcc, off);
    if ((tid & 63) == 0) sRed[tid >> 6] = lossAcc;
    __syncthreads();
    if (tid == 0) {
        float s = 0.f;
#pragma unroll
        for (int w = 0; w < THREADS / 64; ++w) s += sRed[w];
        atomicAdd(out, s * (0.5f / (float)NPIX));
    }

    // flush centroids + counts (counts written as float: harness reads f32)
    for (int i = tid; i < NSEG * D_; i += THREADS) {
        int n = i >> 6, d = i & 63;
        atomicAdd(&out[1 + i], sCent[n][d]);
    }
    if (tid < NSEG) atomicAdd(&out[1 + NSEG * D_ + tid], (float)sCount[tid]);
}

extern "C" void kernel_launch(void* const* d_in, const int* in_sizes, int n_in,
                              void* d_out, int out_size, void* d_ws, size_t ws_size,
                              hipStream_t stream) {
    const float* enc = (const float*)d_in[0];
    const float* wW  = (const float*)d_in[1];
    const float* wC  = (const float*)d_in[2];
    const int*   targ = (const int*)d_in[3];
    float* out = (float*)d_out;

    // d_out is poisoned 0xAA once and never re-poisoned; we accumulate with
    // atomics, so zero it every call (memset node is graph-capturable).
    hipMemsetAsync(d_out, 0, (size_t)out_size * sizeof(float), stream);

    fused_embed<<<dim3(NPIX / TILE), dim3(THREADS), 0, stream>>>(enc, wW, wC, targ, out);
}